// Round 1
// baseline (302.130 us; speedup 1.0000x reference)
//
#include <hip/hip_runtime.h>

#define NN   2048
#define DD   64
#define QB   64      // Q rows per block (16 per wave)
#define KVB  32      // KV rows per iteration
#define BH   32      // B*H

typedef float f32x4 __attribute__((ext_vector_type(4)));
typedef short bf16x8 __attribute__((ext_vector_type(8)));

__device__ __forceinline__ short f2bf(float x){
    unsigned u = __float_as_uint(x);
    u += 0x7FFF + ((u >> 16) & 1);      // round-to-nearest-even
    return (short)(u >> 16);
}

__global__ __launch_bounds__(256)
void attn_fwd(const float* __restrict__ q,
              const float* __restrict__ k,
              const float* __restrict__ v,
              float* __restrict__ out)
{
    const int bh    = blockIdx.y;          // 0..31
    const int qtile = blockIdx.x;          // 0..31
    const int tid   = threadIdx.x;
    const int wave  = tid >> 6;
    const int lane  = tid & 63;
    const int l16   = lane & 15;
    const int lg    = lane >> 4;           // 0..3

    const long base  = (long)bh * NN * DD;
    const int  qrow0 = qtile * QB + wave * 16;

    // per-wave private P buffer; stride 40 bf16 = 80 B (16B-aligned rows, 2-way bank alias only)
    __shared__ __align__(16) short p_lds[4][16][40];

    // ---- load Q fragments, fold in scale = 0.125 (power of two, exact) ----
    bf16x8 aq[2];
    {
        const float* qp = q + base + (long)(qrow0 + l16) * DD + lg * 8;
        #pragma unroll
        for (int c = 0; c < 2; ++c) {
            f32x4 x0 = *(const f32x4*)(qp + c * 32);
            f32x4 x1 = *(const f32x4*)(qp + c * 32 + 4);
            bf16x8 a;
            #pragma unroll
            for (int i = 0; i < 4; ++i) {
                a[i]     = f2bf(x0[i] * 0.125f);
                a[4 + i] = f2bf(x1[i] * 0.125f);
            }
            aq[c] = a;
        }
    }

    float m[4], lsum[4];
    f32x4 acc[4];
    #pragma unroll
    for (int r = 0; r < 4; ++r) { m[r] = -1e30f; lsum[r] = 0.f; }
    #pragma unroll
    for (int t = 0; t < 4; ++t) acc[t] = f32x4{0.f, 0.f, 0.f, 0.f};

    for (int kv0 = 0; kv0 < NN; kv0 += KVB) {
        // ---- QK^T: two 16-col blocks, K-dim = D = 64 (2 MFMA each) ----
        f32x4 s[2];
        #pragma unroll
        for (int cb = 0; cb < 2; ++cb) {
            const float* kp = k + base + (long)(kv0 + cb * 16 + l16) * DD + lg * 8;
            f32x4 z = f32x4{0.f, 0.f, 0.f, 0.f};
            #pragma unroll
            for (int c = 0; c < 2; ++c) {
                f32x4 x0 = *(const f32x4*)(kp + c * 32);
                f32x4 x1 = *(const f32x4*)(kp + c * 32 + 4);
                bf16x8 b;
                #pragma unroll
                for (int i = 0; i < 4; ++i) { b[i] = f2bf(x0[i]); b[4 + i] = f2bf(x1[i]); }
                z = __builtin_amdgcn_mfma_f32_16x16x32_bf16(aq[c], b, z, 0, 0, 0);
            }
            s[cb] = z;
        }

        // ---- online softmax (all 64 lanes active; reduce over the 16 cols) ----
        #pragma unroll
        for (int r = 0; r < 4; ++r) {
            float mx = fmaxf(s[0][r], s[1][r]);
            #pragma unroll
            for (int d = 1; d < 16; d <<= 1) mx = fmaxf(mx, __shfl_xor(mx, d));
            float mn    = fmaxf(m[r], mx);
            float alpha = __expf(m[r] - mn);
            m[r] = mn;
            float p0 = __expf(s[0][r] - mn);
            float p1 = __expf(s[1][r] - mn);
            s[0][r] = p0; s[1][r] = p1;
            float rs = p0 + p1;
            #pragma unroll
            for (int d = 1; d < 16; d <<= 1) rs += __shfl_xor(rs, d);
            lsum[r] = lsum[r] * alpha + rs;
            #pragma unroll
            for (int t = 0; t < 4; ++t) acc[t][r] *= alpha;
        }

        __syncthreads();
        // ---- write P (bf16) to per-wave LDS in S's D-layout ----
        #pragma unroll
        for (int r = 0; r < 4; ++r) {
            int row = lg * 4 + r;
            p_lds[wave][row][l16]      = f2bf(s[0][r]);
            p_lds[wave][row][l16 + 16] = f2bf(s[1][r]);
        }
        __syncthreads();

        // ---- read P as A-fragment (16B ds_read, aligned) ----
        bf16x8 pa = *(const bf16x8*)&p_lds[wave][l16][lg * 8];

        // ---- PV: 4 output col-tiles, K-dim = KVB = 32 (1 MFMA each) ----
        #pragma unroll
        for (int t = 0; t < 4; ++t) {
            const float* vp = v + base + (long)(kv0 + lg * 8) * DD + t * 16 + l16;
            bf16x8 bv;
            #pragma unroll
            for (int i = 0; i < 8; ++i) bv[i] = f2bf(vp[i * DD]);
            acc[t] = __builtin_amdgcn_mfma_f32_16x16x32_bf16(pa, bv, acc[t], 0, 0, 0);
        }
    }

    // ---- epilogue: normalize and store ----
    float* op = out + base + (long)qrow0 * DD;
    #pragma unroll
    for (int r = 0; r < 4; ++r) {
        float inv = 1.f / lsum[r];
        int   row = lg * 4 + r;
        #pragma unroll
        for (int t = 0; t < 4; ++t)
            op[(long)row * DD + t * 16 + l16] = acc[t][r] * inv;
    }
}

extern "C" void kernel_launch(void* const* d_in, const int* in_sizes, int n_in,
                              void* d_out, int out_size, void* d_ws, size_t ws_size,
                              hipStream_t stream) {
    const float* q = (const float*)d_in[0];
    const float* k = (const float*)d_in[1];
    const float* v = (const float*)d_in[2];
    float* out = (float*)d_out;
    dim3 grid(NN / QB, BH);
    attn_fwd<<<grid, 256, 0, stream>>>(q, k, v, out);
}

// Round 2
// 249.551 us; speedup vs baseline: 1.2107x; 1.2107x over previous
//
#include <hip/hip_runtime.h>

#define NN   2048
#define DD   64
#define QB   64      // Q rows per block (16 per wave)
#define KVB  64      // KV rows per iteration
#define BH   32      // B*H
#define BHND (BH * NN * DD)   // 4,194,304 elements per tensor

typedef float f32x4  __attribute__((ext_vector_type(4)));
typedef short bf16x8 __attribute__((ext_vector_type(8)));

__device__ __forceinline__ short f2bf(float x){
    unsigned u = __float_as_uint(x);
    u += 0x7FFF + ((u >> 16) & 1);      // round-to-nearest-even
    return (short)(u >> 16);
}

// ---------------- pre-pass: fp32 -> bf16 (optionally scaled) ----------------
__global__ __launch_bounds__(256)
void cvt_bf16(const float* __restrict__ src, short* __restrict__ dst, float scale)
{
    long i = ((long)blockIdx.x * 256 + threadIdx.x) * 8;
    f32x4 x0 = *(const f32x4*)(src + i);
    f32x4 x1 = *(const f32x4*)(src + i + 4);
    bf16x8 o;
    #pragma unroll
    for (int j = 0; j < 4; ++j) {
        o[j]     = f2bf(x0[j] * scale);
        o[4 + j] = f2bf(x1[j] * scale);
    }
    *(bf16x8*)(dst + i) = o;
}

// ---------------- pre-pass: V [N][D] fp32 -> Vt [D][N] bf16 ----------------
__global__ __launch_bounds__(256)
void vt_kernel(const float* __restrict__ v, short* __restrict__ vt)
{
    const int bh = blockIdx.y;
    const int n0 = blockIdx.x * 64;
    const int tid = threadIdx.x;
    __shared__ __align__(16) short tile[64][72];   // 144-B rows, 16B-aligned

    const float* vb = v + (long)bh * NN * DD;
    const int nl = tid >> 4;          // 0..15
    const int d0 = (tid & 15) * 4;
    #pragma unroll
    for (int pass = 0; pass < 4; ++pass) {
        int n = nl + pass * 16;
        f32x4 x = *(const f32x4*)(vb + (long)(n0 + n) * DD + d0);
        #pragma unroll
        for (int j = 0; j < 4; ++j) tile[d0 + j][n] = f2bf(x[j]);
    }
    __syncthreads();
    short* vtb = vt + (long)bh * DD * NN;
    const int nc = (tid & 7) * 8;
    #pragma unroll
    for (int it = 0; it < 2; ++it) {
        int d = (tid >> 3) + it * 32;
        bf16x8 r = *(const bf16x8*)&tile[d][nc];
        *(bf16x8*)(vtb + (long)d * NN + n0 + nc) = r;
    }
}

// ---------------- main fused attention (bf16 operands) ----------------
__global__ __launch_bounds__(256)
void attn_fwd_bf16(const short* __restrict__ qws,
                   const short* __restrict__ kws,
                   const short* __restrict__ vtws,
                   float* __restrict__ out)
{
    const int bh    = blockIdx.y;
    const int qtile = blockIdx.x;
    const int tid   = threadIdx.x;
    const int wave  = tid >> 6;
    const int lane  = tid & 63;
    const int l16   = lane & 15;
    const int lg    = lane >> 4;

    const long base  = (long)bh * NN * DD;
    const int  qrow0 = qtile * QB + wave * 16;

    // per-wave private P buffer: 16 rows x 64 cols (pad to 72 -> 144-B rows)
    __shared__ __align__(16) short p_lds[4][16][72];

    bf16x8 aq[2];
    #pragma unroll
    for (int c = 0; c < 2; ++c)
        aq[c] = *(const bf16x8*)(qws + base + (long)(qrow0 + l16) * DD + c * 32 + lg * 8);

    float m[4], lsum[4];
    f32x4 acc[4];
    #pragma unroll
    for (int r = 0; r < 4; ++r) { m[r] = -1e30f; lsum[r] = 0.f; }
    #pragma unroll
    for (int t = 0; t < 4; ++t) acc[t] = f32x4{0.f, 0.f, 0.f, 0.f};

    const short* kb  = kws  + base + (long)l16 * DD + lg * 8;
    const short* vtb = vtws + (long)bh * DD * NN + (long)l16 * NN + lg * 8;

    for (int kv0 = 0; kv0 < NN; kv0 += KVB) {
        // ---- QK^T: four 16-col blocks, K-dim = D = 64 ----
        f32x4 s[4];
        #pragma unroll
        for (int cb = 0; cb < 4; ++cb) {
            const short* kp = kb + (long)(kv0 + cb * 16) * DD;
            f32x4 z = f32x4{0.f, 0.f, 0.f, 0.f};
            #pragma unroll
            for (int c = 0; c < 2; ++c) {
                bf16x8 b = *(const bf16x8*)(kp + c * 32);
                z = __builtin_amdgcn_mfma_f32_16x16x32_bf16(aq[c], b, z, 0, 0, 0);
            }
            s[cb] = z;
        }

        // ---- online softmax over 64 columns ----
        #pragma unroll
        for (int r = 0; r < 4; ++r) {
            float mx = fmaxf(fmaxf(s[0][r], s[1][r]), fmaxf(s[2][r], s[3][r]));
            #pragma unroll
            for (int d = 1; d < 16; d <<= 1) mx = fmaxf(mx, __shfl_xor(mx, d));
            float mn    = fmaxf(m[r], mx);
            float alpha = __expf(m[r] - mn);
            m[r] = mn;
            float rs = 0.f;
            #pragma unroll
            for (int cb = 0; cb < 4; ++cb) {
                float p = __expf(s[cb][r] - mn);
                s[cb][r] = p;
                rs += p;
            }
            #pragma unroll
            for (int d = 1; d < 16; d <<= 1) rs += __shfl_xor(rs, d);
            lsum[r] = lsum[r] * alpha + rs;
            #pragma unroll
            for (int t = 0; t < 4; ++t) acc[t][r] *= alpha;
        }

        // ---- P -> per-wave LDS (no barrier needed: wave-private buffer) ----
        #pragma unroll
        for (int r = 0; r < 4; ++r) {
            int row = lg * 4 + r;
            #pragma unroll
            for (int cb = 0; cb < 4; ++cb)
                p_lds[wave][row][cb * 16 + l16] = f2bf(s[cb][r]);
        }

        bf16x8 pa0 = *(const bf16x8*)&p_lds[wave][l16][lg * 8];
        bf16x8 pa1 = *(const bf16x8*)&p_lds[wave][l16][32 + lg * 8];

        // ---- PV: 4 output col-tiles, K-dim = 64 (2 MFMA each) ----
        #pragma unroll
        for (int t = 0; t < 4; ++t) {
            const short* vp = vtb + (long)(t * 16) * NN + kv0;
            bf16x8 bv0 = *(const bf16x8*)vp;
            bf16x8 bv1 = *(const bf16x8*)(vp + 32);
            acc[t] = __builtin_amdgcn_mfma_f32_16x16x32_bf16(pa0, bv0, acc[t], 0, 0, 0);
            acc[t] = __builtin_amdgcn_mfma_f32_16x16x32_bf16(pa1, bv1, acc[t], 0, 0, 0);
        }
    }

    float* op = out + base + (long)qrow0 * DD;
    #pragma unroll
    for (int r = 0; r < 4; ++r) {
        float inv = 1.f / lsum[r];
        int   row = lg * 4 + r;
        #pragma unroll
        for (int t = 0; t < 4; ++t)
            op[(long)row * DD + t * 16 + l16] = acc[t][r] * inv;
    }
}

// ---------------- fallback (fp32 inputs, round-1 kernel) ----------------
__global__ __launch_bounds__(256)
void attn_fwd_f32(const float* __restrict__ q,
                  const float* __restrict__ k,
                  const float* __restrict__ v,
                  float* __restrict__ out)
{
    const int bh    = blockIdx.y;
    const int qtile = blockIdx.x;
    const int tid   = threadIdx.x;
    const int wave  = tid >> 6;
    const int lane  = tid & 63;
    const int l16   = lane & 15;
    const int lg    = lane >> 4;

    const long base  = (long)bh * NN * DD;
    const int  qrow0 = qtile * QB + wave * 16;

    __shared__ __align__(16) short p_lds[4][16][40];

    bf16x8 aq[2];
    {
        const float* qp = q + base + (long)(qrow0 + l16) * DD + lg * 8;
        #pragma unroll
        for (int c = 0; c < 2; ++c) {
            f32x4 x0 = *(const f32x4*)(qp + c * 32);
            f32x4 x1 = *(const f32x4*)(qp + c * 32 + 4);
            bf16x8 a;
            #pragma unroll
            for (int i = 0; i < 4; ++i) { a[i] = f2bf(x0[i] * 0.125f); a[4+i] = f2bf(x1[i] * 0.125f); }
            aq[c] = a;
        }
    }
    float m[4], lsum[4];
    f32x4 acc[4];
    #pragma unroll
    for (int r = 0; r < 4; ++r) { m[r] = -1e30f; lsum[r] = 0.f; }
    #pragma unroll
    for (int t = 0; t < 4; ++t) acc[t] = f32x4{0.f,0.f,0.f,0.f};

    for (int kv0 = 0; kv0 < NN; kv0 += 32) {
        f32x4 s[2];
        #pragma unroll
        for (int cb = 0; cb < 2; ++cb) {
            const float* kp = k + base + (long)(kv0 + cb*16 + l16) * DD + lg * 8;
            f32x4 z = f32x4{0.f,0.f,0.f,0.f};
            #pragma unroll
            for (int c = 0; c < 2; ++c) {
                f32x4 x0 = *(const f32x4*)(kp + c*32);
                f32x4 x1 = *(const f32x4*)(kp + c*32 + 4);
                bf16x8 b;
                #pragma unroll
                for (int i = 0; i < 4; ++i) { b[i] = f2bf(x0[i]); b[4+i] = f2bf(x1[i]); }
                z = __builtin_amdgcn_mfma_f32_16x16x32_bf16(aq[c], b, z, 0, 0, 0);
            }
            s[cb] = z;
        }
        #pragma unroll
        for (int r = 0; r < 4; ++r) {
            float mx = fmaxf(s[0][r], s[1][r]);
            #pragma unroll
            for (int d = 1; d < 16; d <<= 1) mx = fmaxf(mx, __shfl_xor(mx, d));
            float mn = fmaxf(m[r], mx);
            float alpha = __expf(m[r] - mn);
            m[r] = mn;
            float p0 = __expf(s[0][r] - mn);
            float p1 = __expf(s[1][r] - mn);
            s[0][r] = p0; s[1][r] = p1;
            float rs = p0 + p1;
            #pragma unroll
            for (int d = 1; d < 16; d <<= 1) rs += __shfl_xor(rs, d);
            lsum[r] = lsum[r] * alpha + rs;
            #pragma unroll
            for (int t = 0; t < 4; ++t) acc[t][r] *= alpha;
        }
        #pragma unroll
        for (int r = 0; r < 4; ++r) {
            int row = lg * 4 + r;
            p_lds[wave][row][l16]      = f2bf(s[0][r]);
            p_lds[wave][row][l16 + 16] = f2bf(s[1][r]);
        }
        bf16x8 pa = *(const bf16x8*)&p_lds[wave][l16][lg * 8];
        #pragma unroll
        for (int t = 0; t < 4; ++t) {
            const float* vp = v + base + (long)(kv0 + lg * 8) * DD + t * 16 + l16;
            bf16x8 bv;
            #pragma unroll
            for (int i = 0; i < 8; ++i) bv[i] = f2bf(vp[i * DD]);
            acc[t] = __builtin_amdgcn_mfma_f32_16x16x32_bf16(pa, bv, acc[t], 0, 0, 0);
        }
    }
    float* op = out + base + (long)qrow0 * DD;
    #pragma unroll
    for (int r = 0; r < 4; ++r) {
        float inv = 1.f / lsum[r];
        int row = lg * 4 + r;
        #pragma unroll
        for (int t = 0; t < 4; ++t)
            op[(long)row * DD + t * 16 + l16] = acc[t][r] * inv;
    }
}

extern "C" void kernel_launch(void* const* d_in, const int* in_sizes, int n_in,
                              void* d_out, int out_size, void* d_ws, size_t ws_size,
                              hipStream_t stream) {
    const float* q = (const float*)d_in[0];
    const float* k = (const float*)d_in[1];
    const float* v = (const float*)d_in[2];
    float* out = (float*)d_out;
    const size_t need = (size_t)3 * BHND * sizeof(short);

    if (ws_size >= need) {
        short* qws  = (short*)d_ws;
        short* kws  = qws + BHND;
        short* vtws = kws + BHND;
        cvt_bf16<<<BHND / (256 * 8), 256, 0, stream>>>(q, qws, 0.125f);
        cvt_bf16<<<BHND / (256 * 8), 256, 0, stream>>>(k, kws, 1.0f);
        vt_kernel<<<dim3(NN / 64, BH), 256, 0, stream>>>(v, vtws);
        attn_fwd_bf16<<<dim3(NN / QB, BH), 256, 0, stream>>>(qws, kws, vtws, out);
    } else {
        attn_fwd_f32<<<dim3(NN / QB, BH), 256, 0, stream>>>(q, k, v, out);
    }
}

// Round 3
// 97.521 us; speedup vs baseline: 3.0981x; 2.5590x over previous
//
#include <hip/hip_runtime.h>

#define NN   2048
#define DD   64
#define QB   64      // Q rows per block (16 per wave)
#define KVB  64      // KV rows per iteration
#define BH   32      // B*H
#define BHND (BH * NN * DD)

typedef float f32x4   __attribute__((ext_vector_type(4)));
typedef short bf16x8  __attribute__((ext_vector_type(8)));
typedef short bf16x4  __attribute__((ext_vector_type(4)));

__device__ __forceinline__ short f2bf(float x){
    unsigned u = __float_as_uint(x);
    u += 0x7FFF + ((u >> 16) & 1);      // round-to-nearest-even
    return (short)(u >> 16);
}

__device__ __forceinline__ void gload_lds16(const short* g, short* l) {
    __builtin_amdgcn_global_load_lds(
        (const __attribute__((address_space(1))) void*)g,
        (__attribute__((address_space(3))) void*)l, 16, 0, 0);
}

// ---------------- pre-pass: fp32 -> bf16 (optionally scaled) ----------------
__global__ __launch_bounds__(256)
void cvt_bf16(const float* __restrict__ src, short* __restrict__ dst, float scale)
{
    long i = ((long)blockIdx.x * 256 + threadIdx.x) * 8;
    f32x4 x0 = *(const f32x4*)(src + i);
    f32x4 x1 = *(const f32x4*)(src + i + 4);
    bf16x8 o;
    #pragma unroll
    for (int j = 0; j < 4; ++j) {
        o[j]     = f2bf(x0[j] * scale);
        o[4 + j] = f2bf(x1[j] * scale);
    }
    *(bf16x8*)(dst + i) = o;
}

// ---------------- pre-pass: V [N][D] fp32 -> Vt [D][N] bf16 ----------------
__global__ __launch_bounds__(256)
void vt_kernel(const float* __restrict__ v, short* __restrict__ vt)
{
    const int bh = blockIdx.y;
    const int n0 = blockIdx.x * 64;
    const int tid = threadIdx.x;
    __shared__ __align__(16) short tile[64][72];

    const float* vb = v + (long)bh * NN * DD;
    const int nl = tid >> 4;
    const int d0 = (tid & 15) * 4;
    #pragma unroll
    for (int pass = 0; pass < 4; ++pass) {
        int n = nl + pass * 16;
        f32x4 x = *(const f32x4*)(vb + (long)(n0 + n) * DD + d0);
        #pragma unroll
        for (int j = 0; j < 4; ++j) tile[d0 + j][n] = f2bf(x[j]);
    }
    __syncthreads();
    short* vtb = vt + (long)bh * DD * NN;
    const int nc = (tid & 7) * 8;
    #pragma unroll
    for (int it = 0; it < 2; ++it) {
        int d = (tid >> 3) + it * 32;
        bf16x8 r = *(const bf16x8*)&tile[d][nc];
        *(bf16x8*)(vtb + (long)d * NN + n0 + nc) = r;
    }
}

// ---------------- main fused attention v3 ----------------
// swapped QK^T (scores in-lane), block-staged K/Vt in swizzled LDS, dbuf
__global__ __launch_bounds__(256)
void attn_fwd_v3(const short* __restrict__ qws,
                 const short* __restrict__ kws,
                 const short* __restrict__ vtws,
                 float* __restrict__ out)
{
    const int bh    = blockIdx.y;
    const int qtile = blockIdx.x;
    const int tid   = threadIdx.x;
    const int wave  = tid >> 6;
    const int lane  = tid & 63;
    const int l16   = lane & 15;
    const int lg    = lane >> 4;
    const int l7    = l16 & 7;

    // K tile [64 kv][64 d], Vt tile [64 d][64 kv]  (both 128-B rows, XOR-swizzled content)
    __shared__ __align__(16) short k_lds[2][KVB * DD];
    __shared__ __align__(16) short v_lds[2][DD * KVB];
    __shared__ __align__(16) short p_lds[4][16 * KVB];   // per-wave P, swizzled

    const long base  = (long)bh * NN * DD;
    const int  qrow0 = qtile * QB + wave * 16;

    // Q fragments (B-operand layout: lane holds Q[q=l16][d = c*32 + lg*8 + i])
    bf16x8 aq[2];
    #pragma unroll
    for (int c = 0; c < 2; ++c)
        aq[c] = *(const bf16x8*)(qws + base + (long)(qrow0 + l16) * DD + c * 32 + lg * 8);

    // staging: lane covers row (base8 + lane>>3), source col pre-swizzled (involution)
    const int srow = lane >> 3;                 // 0..7
    const int scol = 8 * ((lane & 7) ^ srow);   // shorts
    const short* kg = kws  + base;
    const short* vg = vtws + (long)bh * DD * NN;

    auto stage = [&](int buf, int kv0) {
        #pragma unroll
        for (int j = 0; j < 2; ++j) {
            int b8 = wave * 16 + j * 8;
            gload_lds16(kg + (long)(kv0 + b8 + srow) * DD + scol, &k_lds[buf][b8 * DD]);
        }
        #pragma unroll
        for (int j = 0; j < 2; ++j) {
            int b8 = wave * 16 + j * 8;
            gload_lds16(vg + (long)(b8 + srow) * NN + kv0 + scol, &v_lds[buf][b8 * KVB]);
        }
    };

    float mrun = -1e30f, lrun = 0.f;   // softmax state for q-row = l16
    f32x4 acc[4];
    #pragma unroll
    for (int t = 0; t < 4; ++t) acc[t] = f32x4{0.f, 0.f, 0.f, 0.f};

    int cur = 0;
    stage(0, 0);
    __syncthreads();

    for (int it = 0; it < NN / KVB; ++it) {
        if (it + 1 < NN / KVB) stage(cur ^ 1, (it + 1) * KVB);

        const short* kbuf = k_lds[cur];
        const short* vbuf = v_lds[cur];

        // ---- swapped QK^T: s[cb][r] = S[q=l16][k = cb*16 + lg*4 + r] ----
        f32x4 s[4];
        #pragma unroll
        for (int cb = 0; cb < 4; ++cb) {
            f32x4 z = f32x4{0.f, 0.f, 0.f, 0.f};
            #pragma unroll
            for (int c = 0; c < 2; ++c) {
                bf16x8 ka = *(const bf16x8*)&kbuf[(cb * 16 + l16) * DD +
                                                  ((c * 32 + lg * 8) ^ (l7 << 3))];
                z = __builtin_amdgcn_mfma_f32_16x16x32_bf16(ka, aq[c], z, 0, 0, 0);
            }
            s[cb] = z;
        }

        // ---- online softmax: 15 in-lane fmax + 2 shfl ----
        float mx = s[0][0];
        #pragma unroll
        for (int cb = 0; cb < 4; ++cb)
            #pragma unroll
            for (int r = 0; r < 4; ++r) mx = fmaxf(mx, s[cb][r]);
        mx = fmaxf(mx, __shfl_xor(mx, 16));
        mx = fmaxf(mx, __shfl_xor(mx, 32));
        float mn    = fmaxf(mrun, mx);
        float alpha = __expf(mrun - mn);
        mrun = mn;
        float rs = 0.f;
        #pragma unroll
        for (int cb = 0; cb < 4; ++cb)
            #pragma unroll
            for (int r = 0; r < 4; ++r) {
                float p = __expf(s[cb][r] - mn);
                s[cb][r] = p;
                rs += p;
            }
        rs += __shfl_xor(rs, 16);
        rs += __shfl_xor(rs, 32);
        lrun = lrun * alpha + rs;

        // rescale acc (rows q = lg*4+r): broadcast alpha from lane q'
        #pragma unroll
        for (int r = 0; r < 4; ++r) {
            float ar = __shfl(alpha, lg * 4 + r);
            #pragma unroll
            for (int t = 0; t < 4; ++t) acc[t][r] *= ar;
        }

        // ---- P -> wave-private swizzled LDS (4x ds_write_b64) ----
        #pragma unroll
        for (int cb = 0; cb < 4; ++cb) {
            bf16x4 pk;
            #pragma unroll
            for (int r = 0; r < 4; ++r) pk[r] = f2bf(s[cb][r]);
            *(bf16x4*)&p_lds[wave][l16 * KVB + ((cb * 16 + lg * 4) ^ (l7 << 3))] = pk;
        }

        // ---- PV: pa = A[q=l16][k=kk*32+lg*8+i], bv = Vt rows (swizzled reads) ----
        #pragma unroll
        for (int kk = 0; kk < 2; ++kk) {
            bf16x8 pa = *(const bf16x8*)&p_lds[wave][l16 * KVB +
                                                     ((kk * 32 + lg * 8) ^ (l7 << 3))];
            #pragma unroll
            for (int t = 0; t < 4; ++t) {
                bf16x8 bv = *(const bf16x8*)&vbuf[(t * 16 + l16) * KVB +
                                                  ((kk * 32 + lg * 8) ^ (l7 << 3))];
                acc[t] = __builtin_amdgcn_mfma_f32_16x16x32_bf16(pa, bv, acc[t], 0, 0, 0);
            }
        }

        __syncthreads();
        cur ^= 1;
    }

    // ---- epilogue: rows q = qrow0 + lg*4 + r, cols d = t*16 + l16 ----
    float inv = 1.f / lrun;            // valid for q = l16 (lanes 0..15 hold q'=0..15)
    float* op = out + base + (long)qrow0 * DD;
    #pragma unroll
    for (int r = 0; r < 4; ++r) {
        float ir = __shfl(inv, lg * 4 + r);
        #pragma unroll
        for (int t = 0; t < 4; ++t)
            op[(long)(lg * 4 + r) * DD + t * 16 + l16] = acc[t][r] * ir;
    }
}

extern "C" void kernel_launch(void* const* d_in, const int* in_sizes, int n_in,
                              void* d_out, int out_size, void* d_ws, size_t ws_size,
                              hipStream_t stream) {
    const float* q = (const float*)d_in[0];
    const float* k = (const float*)d_in[1];
    const float* v = (const float*)d_in[2];
    float* out = (float*)d_out;
    const size_t need = (size_t)3 * BHND * sizeof(short);

    short* qws  = (short*)d_ws;
    short* kws  = qws + BHND;
    short* vtws = kws + BHND;
    cvt_bf16<<<BHND / (256 * 8), 256, 0, stream>>>(q, qws, 0.125f);
    cvt_bf16<<<BHND / (256 * 8), 256, 0, stream>>>(k, kws, 1.0f);
    vt_kernel<<<dim3(NN / 64, BH), 256, 0, stream>>>(v, vtws);
    attn_fwd_v3<<<dim3(NN / QB, BH), 256, 0, stream>>>(qws, kws, vtws, out);
    (void)ws_size; (void)need;
}

// Round 4
// 79.443 us; speedup vs baseline: 3.8031x; 1.2276x over previous
//
#include <hip/hip_runtime.h>

#define NN   2048
#define DD   64
#define QB   64      // Q rows per block (16 per wave)
#define KVB  64      // KV rows per iteration
#define BH   32      // B*H
#define BHND (BH * NN * DD)
#define SC   0.18033688f     // 0.125 * log2(e): softmax in exp2 domain
#define THR  11.5415603f     // 8 * log2(e): defer-max threshold

typedef float    f32x4  __attribute__((ext_vector_type(4)));
typedef short    bf16x8 __attribute__((ext_vector_type(8)));
typedef short    bf16x4 __attribute__((ext_vector_type(4)));
typedef unsigned u32x4  __attribute__((ext_vector_type(4)));

__device__ __forceinline__ short f2bf(float x){
    unsigned u = __float_as_uint(x);
    u += 0x7FFF + ((u >> 16) & 1);      // round-to-nearest-even
    return (short)(u >> 16);
}

// packed f32x2 -> bf16x2 (src0 -> low half, pkrtz convention)
__device__ __forceinline__ unsigned cvt_pk(float lo, float hi){
    unsigned r;
    asm("v_cvt_pk_bf16_f32 %0, %1, %2" : "=v"(r) : "v"(lo), "v"(hi));
    return r;
}

__device__ __forceinline__ float exp2_fast(float x){
    float r;
    asm("v_exp_f32 %0, %1" : "=v"(r) : "v"(x));
    return r;
}

__device__ __forceinline__ void gload_lds16(const short* g, short* l) {
    __builtin_amdgcn_global_load_lds(
        (const __attribute__((address_space(1))) void*)g,
        (__attribute__((address_space(3))) void*)l, 16, 0, 0);
}

// ---------------- pre-pass: K fp32 -> bf16 ----------------
__global__ __launch_bounds__(256)
void cvt_bf16(const float* __restrict__ src, short* __restrict__ dst)
{
    long i = ((long)blockIdx.x * 256 + threadIdx.x) * 8;
    f32x4 x0 = *(const f32x4*)(src + i);
    f32x4 x1 = *(const f32x4*)(src + i + 4);
    bf16x8 o;
    #pragma unroll
    for (int j = 0; j < 4; ++j) { o[j] = f2bf(x0[j]); o[4 + j] = f2bf(x1[j]); }
    *(bf16x8*)(dst + i) = o;
}

// ---- pre-pass: V [N][D] fp32 -> Vt [D][N] bf16, kv sigma-permuted per 64-block ----
// slot kappa within each 64-block holds V row sigma(kappa),
// sigma(kk*32+lg*8+i) = (2kk + (i>>2))*16 + lg*4 + (i&3)
__global__ __launch_bounds__(256)
void vt_kernel(const float* __restrict__ v, short* __restrict__ vt)
{
    const int bh = blockIdx.y;
    const int n0 = blockIdx.x * 64;
    const int tid = threadIdx.x;
    __shared__ __align__(16) short tile[64][72];

    const float* vb = v + (long)bh * NN * DD;
    const int nl = tid >> 4;
    const int d0 = (tid & 15) * 4;
    #pragma unroll
    for (int pass = 0; pass < 4; ++pass) {
        int n = nl + pass * 16;
        f32x4 x = *(const f32x4*)(vb + (long)(n0 + n) * DD + d0);
        #pragma unroll
        for (int j = 0; j < 4; ++j) tile[d0 + j][n] = f2bf(x[j]);
    }
    __syncthreads();
    short* vtb = vt + (long)bh * DD * NN;
    const int nc  = (tid & 7) * 8;     // kappa chunk base
    const int kk  = nc >> 5;
    const int lgc = (nc >> 3) & 3;
    #pragma unroll
    for (int itr = 0; itr < 2; ++itr) {
        int d = (tid >> 3) + itr * 32;
        bf16x4 lo = *(const bf16x4*)&tile[d][kk * 32 + lgc * 4];
        bf16x4 hi = *(const bf16x4*)&tile[d][kk * 32 + 16 + lgc * 4];
        bf16x8 r;
        #pragma unroll
        for (int j = 0; j < 4; ++j) { r[j] = lo[j]; r[4 + j] = hi[j]; }
        *(bf16x8*)(vtb + (long)d * NN + n0 + nc) = r;
    }
}

// ---------------- main fused attention v4 ----------------
// swapped QK^T, in-register P (sigma-permuted V), defer-max, exp2 domain
__global__ __launch_bounds__(256)
void attn_fwd_v4(const float* __restrict__ q,
                 const short* __restrict__ kws,
                 const short* __restrict__ vtws,
                 float* __restrict__ out)
{
    const int bh    = blockIdx.y;
    const int qtile = blockIdx.x;
    const int tid   = threadIdx.x;
    const int wave  = tid >> 6;
    const int lane  = tid & 63;
    const int l16   = lane & 15;
    const int lg    = lane >> 4;
    const int l7    = l16 & 7;

    __shared__ __align__(16) short k_lds[2][KVB * DD];   // 16 KB
    __shared__ __align__(16) short v_lds[2][DD * KVB];   // 16 KB

    const long base  = (long)bh * NN * DD;
    const int  qrow0 = qtile * QB + wave * 16;

    // ---- load Q, convert in-register with scale SC (exp2 domain) ----
    bf16x8 aq[2];
    {
        const float* qp = q + base + (long)(qrow0 + l16) * DD + lg * 8;
        #pragma unroll
        for (int c = 0; c < 2; ++c) {
            f32x4 x0 = *(const f32x4*)(qp + c * 32);
            f32x4 x1 = *(const f32x4*)(qp + c * 32 + 4);
            u32x4 pk;
            pk[0] = cvt_pk(x0[0] * SC, x0[1] * SC);
            pk[1] = cvt_pk(x0[2] * SC, x0[3] * SC);
            pk[2] = cvt_pk(x1[0] * SC, x1[1] * SC);
            pk[3] = cvt_pk(x1[2] * SC, x1[3] * SC);
            aq[c] = __builtin_bit_cast(bf16x8, pk);
        }
    }

    // staging: lane covers row (lane>>3), source col block pre-swizzled (involution)
    const int srow = lane >> 3;
    const int scol = 8 * ((lane & 7) ^ srow);
    const short* kg = kws  + base;
    const short* vg = vtws + (long)bh * DD * NN;

    auto stage = [&](int buf, int kv0) {
        #pragma unroll
        for (int j = 0; j < 2; ++j) {
            int b8 = wave * 16 + j * 8;
            gload_lds16(kg + (long)(kv0 + b8 + srow) * DD + scol, &k_lds[buf][b8 * DD]);
        }
        #pragma unroll
        for (int j = 0; j < 2; ++j) {
            int b8 = wave * 16 + j * 8;
            gload_lds16(vg + (long)(b8 + srow) * NN + kv0 + scol, &v_lds[buf][b8 * KVB]);
        }
    };

    float mrun = -1e30f, lrun = 0.f;   // state for q-row = l16 (replicated over lg)
    f32x4 acc[4];
    #pragma unroll
    for (int t = 0; t < 4; ++t) acc[t] = f32x4{0.f, 0.f, 0.f, 0.f};

    int cur = 0;
    stage(0, 0);
    __syncthreads();

    for (int it = 0; it < NN / KVB; ++it) {
        if (it + 1 < NN / KVB) stage(cur ^ 1, (it + 1) * KVB);

        const short* kbuf = k_lds[cur];
        const short* vbuf = v_lds[cur];

        // ---- swapped QK^T: s[cb][r] = S[q=l16][kv = cb*16 + lg*4 + r] ----
        f32x4 s[4];
        __builtin_amdgcn_s_setprio(1);
        #pragma unroll
        for (int cb = 0; cb < 4; ++cb) {
            f32x4 z = f32x4{0.f, 0.f, 0.f, 0.f};
            #pragma unroll
            for (int c = 0; c < 2; ++c) {
                bf16x8 ka = *(const bf16x8*)&kbuf[(cb * 16 + l16) * DD +
                                                  ((c * 32 + lg * 8) ^ (l7 << 3))];
                z = __builtin_amdgcn_mfma_f32_16x16x32_bf16(ka, aq[c], z, 0, 0, 0);
            }
            s[cb] = z;
        }
        __builtin_amdgcn_s_setprio(0);

        // ---- online softmax (exp2 domain), defer-max ----
        float mx = s[0][0];
        #pragma unroll
        for (int cb = 0; cb < 4; ++cb)
            #pragma unroll
            for (int r = 0; r < 4; ++r) mx = fmaxf(mx, s[cb][r]);
        mx = fmaxf(mx, __shfl_xor(mx, 16));
        mx = fmaxf(mx, __shfl_xor(mx, 32));

        if (!__all(mx - mrun <= THR)) {
            float mn    = fmaxf(mrun, mx);
            float alpha = exp2_fast(mrun - mn);
            mrun = mn;
            lrun *= alpha;
            #pragma unroll
            for (int r = 0; r < 4; ++r) {
                float ar = __shfl(alpha, lg * 4 + r);
                #pragma unroll
                for (int t = 0; t < 4; ++t) acc[t][r] *= ar;
            }
        }

        float rs = 0.f;
        #pragma unroll
        for (int cb = 0; cb < 4; ++cb)
            #pragma unroll
            for (int r = 0; r < 4; ++r) {
                float p = exp2_fast(s[cb][r] - mrun);
                s[cb][r] = p;
                rs += p;
            }
        rs += __shfl_xor(rs, 16);
        rs += __shfl_xor(rs, 32);
        lrun += rs;

        // ---- pack P in-register: pa[kk][i] = s[2kk + (i>>2)][i&3] ----
        u32x4 w0, w1;
        w0[0] = cvt_pk(s[0][0], s[0][1]);  w0[1] = cvt_pk(s[0][2], s[0][3]);
        w0[2] = cvt_pk(s[1][0], s[1][1]);  w0[3] = cvt_pk(s[1][2], s[1][3]);
        w1[0] = cvt_pk(s[2][0], s[2][1]);  w1[1] = cvt_pk(s[2][2], s[2][3]);
        w1[2] = cvt_pk(s[3][0], s[3][1]);  w1[3] = cvt_pk(s[3][2], s[3][3]);
        bf16x8 pa0 = __builtin_bit_cast(bf16x8, w0);
        bf16x8 pa1 = __builtin_bit_cast(bf16x8, w1);

        // ---- PV: bv rows are sigma-permuted V, matching pa slots ----
        __builtin_amdgcn_s_setprio(1);
        #pragma unroll
        for (int t = 0; t < 4; ++t) {
            bf16x8 bv0 = *(const bf16x8*)&vbuf[(t * 16 + l16) * KVB +
                                               ((lg * 8) ^ (l7 << 3))];
            bf16x8 bv1 = *(const bf16x8*)&vbuf[(t * 16 + l16) * KVB +
                                               ((32 + lg * 8) ^ (l7 << 3))];
            acc[t] = __builtin_amdgcn_mfma_f32_16x16x32_bf16(pa0, bv0, acc[t], 0, 0, 0);
            acc[t] = __builtin_amdgcn_mfma_f32_16x16x32_bf16(pa1, bv1, acc[t], 0, 0, 0);
        }
        __builtin_amdgcn_s_setprio(0);

        __syncthreads();
        cur ^= 1;
    }

    // ---- epilogue ----
    float inv = 1.f / lrun;            // valid at lane l16 = q
    float* op = out + base + (long)qrow0 * DD;
    #pragma unroll
    for (int r = 0; r < 4; ++r) {
        float ir = __shfl(inv, lg * 4 + r);
        #pragma unroll
        for (int t = 0; t < 4; ++t)
            op[(long)(lg * 4 + r) * DD + t * 16 + l16] = acc[t][r] * ir;
    }
}

extern "C" void kernel_launch(void* const* d_in, const int* in_sizes, int n_in,
                              void* d_out, int out_size, void* d_ws, size_t ws_size,
                              hipStream_t stream) {
    const float* q = (const float*)d_in[0];
    const float* k = (const float*)d_in[1];
    const float* v = (const float*)d_in[2];
    float* out = (float*)d_out;

    short* kws  = (short*)d_ws;
    short* vtws = kws + BHND;
    cvt_bf16<<<BHND / (256 * 8), 256, 0, stream>>>(k, kws);
    vt_kernel<<<dim3(NN / 64, BH), 256, 0, stream>>>(v, vtws);
    attn_fwd_v4<<<dim3(NN / QB, BH), 256, 0, stream>>>(q, kws, vtws, out);
    (void)ws_size;
}

// Round 5
// 76.461 us; speedup vs baseline: 3.9514x; 1.0390x over previous
//
#include <hip/hip_runtime.h>

#define NN   2048
#define DD   64
#define QB   64      // Q rows per block (16 per wave)
#define KVB  64      // KV rows per iteration
#define NT   (NN / KVB)
#define BH   32      // B*H
#define BHND (BH * NN * DD)
#define SC   0.18033688f     // 0.125 * log2(e): softmax in exp2 domain
#define THR  11.5415603f     // 8 * log2(e): defer-max threshold

typedef float    f32x4  __attribute__((ext_vector_type(4)));
typedef short    bf16x8 __attribute__((ext_vector_type(8)));
typedef short    bf16x4 __attribute__((ext_vector_type(4)));
typedef unsigned u32x4  __attribute__((ext_vector_type(4)));

#define WAIT_VM4()   asm volatile("s_waitcnt vmcnt(4)" ::: "memory")
#define WAIT_VM0()   asm volatile("s_waitcnt vmcnt(0)" ::: "memory")
#define WAIT_LGKM0() asm volatile("s_waitcnt lgkmcnt(0)" ::: "memory")
#define SBAR()       __builtin_amdgcn_s_barrier()
#define SFENCE()     __builtin_amdgcn_sched_barrier(0)

__device__ __forceinline__ short f2bf(float x){
    unsigned u = __float_as_uint(x);
    u += 0x7FFF + ((u >> 16) & 1);      // round-to-nearest-even
    return (short)(u >> 16);
}

__device__ __forceinline__ unsigned cvt_pk(float lo, float hi){
    unsigned r;
    asm("v_cvt_pk_bf16_f32 %0, %1, %2" : "=v"(r) : "v"(lo), "v"(hi));
    return r;
}

__device__ __forceinline__ float exp2_fast(float x){
    float r;
    asm("v_exp_f32 %0, %1" : "=v"(r) : "v"(x));
    return r;
}

__device__ __forceinline__ float max3f(float a, float b, float c){
    return fmaxf(fmaxf(a, b), c);       // clang fuses to v_max3_f32
}

__device__ __forceinline__ void gload_lds16(const short* g, short* l) {
    __builtin_amdgcn_global_load_lds(
        (const __attribute__((address_space(1))) void*)g,
        (__attribute__((address_space(3))) void*)l, 16, 0, 0);
}

// ---------------- merged pre-pass ----------------
// z=0: K fp32 -> bf16.  z=1 (x<32): V [N][D] fp32 -> Vt [D][N] bf16, sigma-permuted.
__global__ __launch_bounds__(256)
void prep(const float* __restrict__ k, const float* __restrict__ v,
          short* __restrict__ kws, short* __restrict__ vtws)
{
    const int tid = threadIdx.x;
    if (blockIdx.z == 0) {
        long i = (((long)blockIdx.y * 64 + blockIdx.x) * 256 + tid) * 8;
        f32x4 x0 = *(const f32x4*)(k + i);
        f32x4 x1 = *(const f32x4*)(k + i + 4);
        bf16x8 o;
        #pragma unroll
        for (int j = 0; j < 4; ++j) { o[j] = f2bf(x0[j]); o[4 + j] = f2bf(x1[j]); }
        *(bf16x8*)(kws + i) = o;
        return;
    }
    if (blockIdx.x >= 32) return;
    const int bh = blockIdx.y;
    const int n0 = blockIdx.x * 64;
    __shared__ __align__(16) short tile[64][72];

    const float* vb = v + (long)bh * NN * DD;
    const int nl = tid >> 4;
    const int d0 = (tid & 15) * 4;
    #pragma unroll
    for (int pass = 0; pass < 4; ++pass) {
        int n = nl + pass * 16;
        f32x4 x = *(const f32x4*)(vb + (long)(n0 + n) * DD + d0);
        #pragma unroll
        for (int j = 0; j < 4; ++j) tile[d0 + j][n] = f2bf(x[j]);
    }
    __syncthreads();
    short* vtb = vtws + (long)bh * DD * NN;
    const int nc  = (tid & 7) * 8;
    const int kk  = nc >> 5;
    const int lgc = (nc >> 3) & 3;
    #pragma unroll
    for (int itr = 0; itr < 2; ++itr) {
        int d = (tid >> 3) + itr * 32;
        bf16x4 lo = *(const bf16x4*)&tile[d][kk * 32 + lgc * 4];
        bf16x4 hi = *(const bf16x4*)&tile[d][kk * 32 + 16 + lgc * 4];
        bf16x8 r;
        #pragma unroll
        for (int j = 0; j < 4; ++j) { r[j] = lo[j]; r[4 + j] = hi[j]; }
        *(bf16x8*)(vtb + (long)d * NN + n0 + nc) = r;
    }
}

// ---------------- main fused attention v5 ----------------
// counted-vmcnt 2-deep pipeline, XCD-swizzled grid, in-register P
__global__ __launch_bounds__(256)
void attn_fwd_v5(const float* __restrict__ q,
                 const short* __restrict__ kws,
                 const short* __restrict__ vtws,
                 float* __restrict__ out)
{
    // bijective XCD swizzle: all 32 q-tiles of one bh land on one XCD
    const int l     = blockIdx.x;        // 0..1023
    const int xcd   = l & 7;
    const int idx   = l >> 3;            // 0..127
    const int qtile = idx & 31;
    const int bh    = xcd + 8 * (idx >> 5);

    const int tid   = threadIdx.x;
    const int wave  = tid >> 6;
    const int lane  = tid & 63;
    const int l16   = lane & 15;
    const int lg    = lane >> 4;
    const int l7    = l16 & 7;

    __shared__ __align__(16) short k_lds[2][KVB * DD];   // 16 KB
    __shared__ __align__(16) short v_lds[2][DD * KVB];   // 16 KB

    const long base  = (long)bh * NN * DD;
    const int  qrow0 = qtile * QB + wave * 16;

    // ---- load Q, convert in-register with scale SC (exp2 domain) ----
    bf16x8 aq[2];
    {
        const float* qp = q + base + (long)(qrow0 + l16) * DD + lg * 8;
        #pragma unroll
        for (int c = 0; c < 2; ++c) {
            f32x4 x0 = *(const f32x4*)(qp + c * 32);
            f32x4 x1 = *(const f32x4*)(qp + c * 32 + 4);
            u32x4 pk;
            pk[0] = cvt_pk(x0[0] * SC, x0[1] * SC);
            pk[1] = cvt_pk(x0[2] * SC, x0[3] * SC);
            pk[2] = cvt_pk(x1[0] * SC, x1[1] * SC);
            pk[3] = cvt_pk(x1[2] * SC, x1[3] * SC);
            aq[c] = __builtin_bit_cast(bf16x8, pk);
        }
    }

    // staging: lane covers row (lane>>3), source col block pre-swizzled (involution)
    const int srow = lane >> 3;
    const int scol = 8 * ((lane & 7) ^ srow);
    const short* kg = kws  + base;
    const short* vg = vtws + (long)bh * DD * NN;

    auto stage = [&](int buf, int kv0) {
        #pragma unroll
        for (int j = 0; j < 2; ++j) {
            int b8 = wave * 16 + j * 8;
            gload_lds16(kg + (long)(kv0 + b8 + srow) * DD + scol, &k_lds[buf][b8 * DD]);
        }
        #pragma unroll
        for (int j = 0; j < 2; ++j) {
            int b8 = wave * 16 + j * 8;
            gload_lds16(vg + (long)(b8 + srow) * NN + kv0 + scol, &v_lds[buf][b8 * KVB]);
        }
    };

    float mrun = -1e30f, lrun = 0.f;   // state for q-row = l16 (replicated over lg)
    f32x4 acc[4];
    #pragma unroll
    for (int t = 0; t < 4; ++t) acc[t] = f32x4{0.f, 0.f, 0.f, 0.f};

    int cur = 0;
    stage(0, 0);
    stage(1, KVB);

    for (int t = 0; t < NT; ++t) {
        // stage(t) landed for all waves; stage(t+1) stays in flight across the barrier
        if (t == NT - 1) { WAIT_VM0(); } else { WAIT_VM4(); }
        SBAR(); SFENCE();

        const short* kbuf = k_lds[cur];
        const short* vbuf = v_lds[cur];

        // ---- swapped QK^T: s[cb][r] = S[q=l16][kv = cb*16 + lg*4 + r] ----
        f32x4 s[4];
        __builtin_amdgcn_s_setprio(1);
        #pragma unroll
        for (int cb = 0; cb < 4; ++cb) {
            f32x4 z = f32x4{0.f, 0.f, 0.f, 0.f};
            #pragma unroll
            for (int c = 0; c < 2; ++c) {
                bf16x8 ka = *(const bf16x8*)&kbuf[(cb * 16 + l16) * DD +
                                                  ((c * 32 + lg * 8) ^ (l7 << 3))];
                z = __builtin_amdgcn_mfma_f32_16x16x32_bf16(ka, aq[c], z, 0, 0, 0);
            }
            s[cb] = z;
        }
        __builtin_amdgcn_s_setprio(0);

        // ---- online softmax (exp2 domain), defer-max, max3 tree ----
        float t0 = max3f(s[0][0], s[0][1], s[0][2]);
        float t1 = max3f(s[0][3], s[1][0], s[1][1]);
        float t2 = max3f(s[1][2], s[1][3], s[2][0]);
        float t3 = max3f(s[2][1], s[2][2], s[2][3]);
        float t4 = max3f(s[3][0], s[3][1], s[3][2]);
        float mx = max3f(max3f(t0, t1, t2), fmaxf(t3, t4), s[3][3]);
        mx = fmaxf(mx, __shfl_xor(mx, 16));
        mx = fmaxf(mx, __shfl_xor(mx, 32));

        if (!__all(mx - mrun <= THR)) {
            float mn    = fmaxf(mrun, mx);
            float alpha = exp2_fast(mrun - mn);
            mrun = mn;
            lrun *= alpha;
            #pragma unroll
            for (int r = 0; r < 4; ++r) {
                float ar = __shfl(alpha, lg * 4 + r);
                #pragma unroll
                for (int t2i = 0; t2i < 4; ++t2i) acc[t2i][r] *= ar;
            }
        }

        float rs = 0.f;
        #pragma unroll
        for (int cb = 0; cb < 4; ++cb)
            #pragma unroll
            for (int r = 0; r < 4; ++r) {
                float p = exp2_fast(s[cb][r] - mrun);
                s[cb][r] = p;
                rs += p;
            }
        rs += __shfl_xor(rs, 16);
        rs += __shfl_xor(rs, 32);
        lrun += rs;

        // ---- pack P in-register: pa[kk][i] = s[2kk + (i>>2)][i&3] ----
        u32x4 w0, w1;
        w0[0] = cvt_pk(s[0][0], s[0][1]);  w0[1] = cvt_pk(s[0][2], s[0][3]);
        w0[2] = cvt_pk(s[1][0], s[1][1]);  w0[3] = cvt_pk(s[1][2], s[1][3]);
        w1[0] = cvt_pk(s[2][0], s[2][1]);  w1[1] = cvt_pk(s[2][2], s[2][3]);
        w1[2] = cvt_pk(s[3][0], s[3][1]);  w1[3] = cvt_pk(s[3][2], s[3][3]);
        bf16x8 pa0 = __builtin_bit_cast(bf16x8, w0);
        bf16x8 pa1 = __builtin_bit_cast(bf16x8, w1);

        // ---- PV: bv rows are sigma-permuted V, matching pa slots ----
        __builtin_amdgcn_s_setprio(1);
        #pragma unroll
        for (int t2i = 0; t2i < 4; ++t2i) {
            bf16x8 bv0 = *(const bf16x8*)&vbuf[(t2i * 16 + l16) * KVB +
                                               ((lg * 8) ^ (l7 << 3))];
            bf16x8 bv1 = *(const bf16x8*)&vbuf[(t2i * 16 + l16) * KVB +
                                               ((32 + lg * 8) ^ (l7 << 3))];
            acc[t2i] = __builtin_amdgcn_mfma_f32_16x16x32_bf16(pa0, bv0, acc[t2i], 0, 0, 0);
            acc[t2i] = __builtin_amdgcn_mfma_f32_16x16x32_bf16(pa1, bv1, acc[t2i], 0, 0, 0);
        }
        __builtin_amdgcn_s_setprio(0);

        // ---- re-stage this buffer 2 tiles ahead (no vmcnt drain) ----
        if (t + 2 < NT) {
            SFENCE();
            WAIT_LGKM0();       // my reads of buf[cur] are done
            SBAR(); SFENCE();   // everyone's reads are done
            stage(cur, (t + 2) * KVB);
        }
        cur ^= 1;
    }

    // ---- epilogue ----
    float inv = 1.f / lrun;            // valid at lane l16 = q
    float* op = out + base + (long)qrow0 * DD;
    #pragma unroll
    for (int r = 0; r < 4; ++r) {
        float ir = __shfl(inv, lg * 4 + r);
        #pragma unroll
        for (int t2i = 0; t2i < 4; ++t2i)
            op[(long)(lg * 4 + r) * DD + t2i * 16 + l16] = acc[t2i][r] * ir;
    }
}

extern "C" void kernel_launch(void* const* d_in, const int* in_sizes, int n_in,
                              void* d_out, int out_size, void* d_ws, size_t ws_size,
                              hipStream_t stream) {
    const float* q = (const float*)d_in[0];
    const float* k = (const float*)d_in[1];
    const float* v = (const float*)d_in[2];
    float* out = (float*)d_out;

    short* kws  = (short*)d_ws;
    short* vtws = kws + BHND;
    prep<<<dim3(64, 32, 2), 256, 0, stream>>>(k, v, kws, vtws);
    attn_fwd_v5<<<1024, 256, 0, stream>>>(q, kws, vtws, out);
    (void)ws_size;
}

// Round 6
// 75.091 us; speedup vs baseline: 4.0235x; 1.0182x over previous
//
#include <hip/hip_runtime.h>

#define NN   2048
#define DD   64
#define QB   64      // Q rows per block (32 per wave, 2 waves)
#define KVB  64      // KV rows per iteration
#define NT   (NN / KVB)
#define BH   32      // B*H
#define BHND (BH * NN * DD)
#define SC   0.18033688f     // 0.125 * log2(e): softmax in exp2 domain
#define THR  11.5415603f     // 8 * log2(e): defer-max threshold

typedef float    f32x4  __attribute__((ext_vector_type(4)));
typedef short    bf16x8 __attribute__((ext_vector_type(8)));
typedef short    bf16x4 __attribute__((ext_vector_type(4)));
typedef unsigned u32x4  __attribute__((ext_vector_type(4)));

#define WAIT_VM8()   asm volatile("s_waitcnt vmcnt(8)" ::: "memory")
#define WAIT_VM0()   asm volatile("s_waitcnt vmcnt(0)" ::: "memory")
#define WAIT_LGKM0() asm volatile("s_waitcnt lgkmcnt(0)" ::: "memory")
#define SBAR()       __builtin_amdgcn_s_barrier()
#define SFENCE()     __builtin_amdgcn_sched_barrier(0)

__device__ __forceinline__ short f2bf(float x){
    unsigned u = __float_as_uint(x);
    u += 0x7FFF + ((u >> 16) & 1);      // round-to-nearest-even
    return (short)(u >> 16);
}

__device__ __forceinline__ unsigned cvt_pk(float lo, float hi){
    unsigned r;
    asm("v_cvt_pk_bf16_f32 %0, %1, %2" : "=v"(r) : "v"(lo), "v"(hi));
    return r;
}

__device__ __forceinline__ float exp2_fast(float x){
    float r;
    asm("v_exp_f32 %0, %1" : "=v"(r) : "v"(x));
    return r;
}

__device__ __forceinline__ float max3f(float a, float b, float c){
    return fmaxf(fmaxf(a, b), c);       // clang fuses to v_max3_f32
}

__device__ __forceinline__ void gload_lds16(const short* g, short* l) {
    __builtin_amdgcn_global_load_lds(
        (const __attribute__((address_space(1))) void*)g,
        (__attribute__((address_space(3))) void*)l, 16, 0, 0);
}

// ---------------- merged pre-pass ----------------
// z=0: K fp32 -> bf16.  z=1 (x<32): V [N][D] fp32 -> Vt [D][N] bf16, sigma-permuted.
__global__ __launch_bounds__(256)
void prep(const float* __restrict__ k, const float* __restrict__ v,
          short* __restrict__ kws, short* __restrict__ vtws)
{
    const int tid = threadIdx.x;
    if (blockIdx.z == 0) {
        long i = (((long)blockIdx.y * 64 + blockIdx.x) * 256 + tid) * 8;
        f32x4 x0 = *(const f32x4*)(k + i);
        f32x4 x1 = *(const f32x4*)(k + i + 4);
        bf16x8 o;
        #pragma unroll
        for (int j = 0; j < 4; ++j) { o[j] = f2bf(x0[j]); o[4 + j] = f2bf(x1[j]); }
        *(bf16x8*)(kws + i) = o;
        return;
    }
    if (blockIdx.x >= 32) return;
    const int bh = blockIdx.y;
    const int n0 = blockIdx.x * 64;
    __shared__ __align__(16) short tile[64][72];

    const float* vb = v + (long)bh * NN * DD;
    const int nl = tid >> 4;
    const int d0 = (tid & 15) * 4;
    #pragma unroll
    for (int pass = 0; pass < 4; ++pass) {
        int n = nl + pass * 16;
        f32x4 x = *(const f32x4*)(vb + (long)(n0 + n) * DD + d0);
        #pragma unroll
        for (int j = 0; j < 4; ++j) tile[d0 + j][n] = f2bf(x[j]);
    }
    __syncthreads();
    short* vtb = vtws + (long)bh * DD * NN;
    const int nc  = (tid & 7) * 8;
    const int kk  = nc >> 5;
    const int lgc = (nc >> 3) & 3;
    #pragma unroll
    for (int itr = 0; itr < 2; ++itr) {
        int d = (tid >> 3) + itr * 32;
        bf16x4 lo = *(const bf16x4*)&tile[d][kk * 32 + lgc * 4];
        bf16x4 hi = *(const bf16x4*)&tile[d][kk * 32 + 16 + lgc * 4];
        bf16x8 r;
        #pragma unroll
        for (int j = 0; j < 4; ++j) { r[j] = lo[j]; r[4 + j] = hi[j]; }
        *(bf16x8*)(vtb + (long)d * NN + n0 + nc) = r;
    }
}

// ---------------- main fused attention v6 ----------------
// 32 q-rows/wave (2 sub-blocks share every LDS fragment read), 2-wave blocks,
// counted-vmcnt 2-deep pipeline, XCD-swizzled grid, in-register P
__global__ __launch_bounds__(128)
void attn_fwd_v6(const float* __restrict__ q,
                 const short* __restrict__ kws,
                 const short* __restrict__ vtws,
                 float* __restrict__ out)
{
    // bijective XCD swizzle: all 32 q-tiles of one bh land on one XCD
    const int l     = blockIdx.x;        // 0..1023
    const int xcd   = l & 7;
    const int idx   = l >> 3;            // 0..127
    const int qtile = idx & 31;
    const int bh    = xcd + 8 * (idx >> 5);

    const int tid   = threadIdx.x;       // 0..127
    const int wave  = tid >> 6;          // 0..1
    const int lane  = tid & 63;
    const int l16   = lane & 15;
    const int lg    = lane >> 4;
    const int l7    = l16 & 7;

    __shared__ __align__(16) short k_lds[2][KVB * DD];   // 16 KB
    __shared__ __align__(16) short v_lds[2][DD * KVB];   // 16 KB

    const long base  = (long)bh * NN * DD;
    const int  qrow0 = qtile * QB + wave * 32;

    // ---- load Q (2 sub-blocks of 16 rows), convert with scale SC ----
    bf16x8 aq[2][2];                     // [sub-block j][c]
    #pragma unroll
    for (int j = 0; j < 2; ++j) {
        const float* qp = q + base + (long)(qrow0 + j * 16 + l16) * DD + lg * 8;
        #pragma unroll
        for (int c = 0; c < 2; ++c) {
            f32x4 x0 = *(const f32x4*)(qp + c * 32);
            f32x4 x1 = *(const f32x4*)(qp + c * 32 + 4);
            u32x4 pk;
            pk[0] = cvt_pk(x0[0] * SC, x0[1] * SC);
            pk[1] = cvt_pk(x0[2] * SC, x0[3] * SC);
            pk[2] = cvt_pk(x1[0] * SC, x1[1] * SC);
            pk[3] = cvt_pk(x1[2] * SC, x1[3] * SC);
            aq[j][c] = __builtin_bit_cast(bf16x8, pk);
        }
    }

    // staging: lane covers row (lane>>3) within an 8-row group; col pre-swizzled
    const int srow = lane >> 3;
    const int scol = 8 * ((lane & 7) ^ srow);
    const short* kg = kws  + base;
    const short* vg = vtws + (long)bh * DD * NN;

    auto stage = [&](int buf, int kv0) {
        #pragma unroll
        for (int j = 0; j < 4; ++j) {
            int b8 = wave * 32 + j * 8;
            gload_lds16(kg + (long)(kv0 + b8 + srow) * DD + scol, &k_lds[buf][b8 * DD]);
        }
        #pragma unroll
        for (int j = 0; j < 4; ++j) {
            int b8 = wave * 32 + j * 8;
            gload_lds16(vg + (long)(b8 + srow) * NN + kv0 + scol, &v_lds[buf][b8 * KVB]);
        }
    };

    float mrun[2] = {-1e30f, -1e30f}, lrun[2] = {0.f, 0.f};
    f32x4 acc[4][2];
    #pragma unroll
    for (int t = 0; t < 4; ++t)
        #pragma unroll
        for (int j = 0; j < 2; ++j) acc[t][j] = f32x4{0.f, 0.f, 0.f, 0.f};

    int cur = 0;
    stage(0, 0);
    stage(1, KVB);

    for (int t = 0; t < NT; ++t) {
        // stage(t) landed; stage(t+1)'s 8 loads stay in flight across the barrier
        if (t == NT - 1) { WAIT_VM0(); } else { WAIT_VM8(); }
        SBAR(); SFENCE();

        const short* kbuf = k_lds[cur];
        const short* vbuf = v_lds[cur];

        // ---- swapped QK^T: s[cb][j][r] = S[q = j*16+l16][kv = cb*16+lg*4+r] ----
        f32x4 s[4][2];
        __builtin_amdgcn_s_setprio(1);
        #pragma unroll
        for (int cb = 0; cb < 4; ++cb) {
            bf16x8 ka0 = *(const bf16x8*)&kbuf[(cb * 16 + l16) * DD +
                                               ((lg * 8) ^ (l7 << 3))];
            bf16x8 ka1 = *(const bf16x8*)&kbuf[(cb * 16 + l16) * DD +
                                               ((32 + lg * 8) ^ (l7 << 3))];
            #pragma unroll
            for (int j = 0; j < 2; ++j) {
                f32x4 z = f32x4{0.f, 0.f, 0.f, 0.f};
                z = __builtin_amdgcn_mfma_f32_16x16x32_bf16(ka0, aq[j][0], z, 0, 0, 0);
                z = __builtin_amdgcn_mfma_f32_16x16x32_bf16(ka1, aq[j][1], z, 0, 0, 0);
                s[cb][j] = z;
            }
        }
        __builtin_amdgcn_s_setprio(0);

        // ---- online softmax (exp2 domain), defer-max, per sub-block ----
        float mx[2];
        #pragma unroll
        for (int j = 0; j < 2; ++j) {
            float t0 = max3f(s[0][j][0], s[0][j][1], s[0][j][2]);
            float t1 = max3f(s[0][j][3], s[1][j][0], s[1][j][1]);
            float t2 = max3f(s[1][j][2], s[1][j][3], s[2][j][0]);
            float t3 = max3f(s[2][j][1], s[2][j][2], s[2][j][3]);
            float t4 = max3f(s[3][j][0], s[3][j][1], s[3][j][2]);
            float m  = max3f(max3f(t0, t1, t2), fmaxf(t3, t4), s[3][j][3]);
            m = fmaxf(m, __shfl_xor(m, 16));
            m = fmaxf(m, __shfl_xor(m, 32));
            mx[j] = m;
        }

        bool need = (mx[0] - mrun[0] > THR) || (mx[1] - mrun[1] > THR);
        if (__any(need)) {
            #pragma unroll
            for (int j = 0; j < 2; ++j) {
                float mn    = fmaxf(mrun[j], mx[j]);
                float alpha = exp2_fast(mrun[j] - mn);
                mrun[j] = mn;
                lrun[j] *= alpha;
                #pragma unroll
                for (int r = 0; r < 4; ++r) {
                    float ar = __shfl(alpha, lg * 4 + r);
                    #pragma unroll
                    for (int t2 = 0; t2 < 4; ++t2) acc[t2][j][r] *= ar;
                }
            }
        }

        #pragma unroll
        for (int j = 0; j < 2; ++j) {
            float rs = 0.f;
            #pragma unroll
            for (int cb = 0; cb < 4; ++cb)
                #pragma unroll
                for (int r = 0; r < 4; ++r) {
                    float p = exp2_fast(s[cb][j][r] - mrun[j]);
                    s[cb][j][r] = p;
                    rs += p;
                }
            rs += __shfl_xor(rs, 16);
            rs += __shfl_xor(rs, 32);
            lrun[j] += rs;
        }

        // ---- pack P in-register: pa[j][kk][i] = s[2kk+(i>>2)][j][i&3] ----
        bf16x8 pa[2][2];
        #pragma unroll
        for (int j = 0; j < 2; ++j) {
            u32x4 w0, w1;
            w0[0] = cvt_pk(s[0][j][0], s[0][j][1]);  w0[1] = cvt_pk(s[0][j][2], s[0][j][3]);
            w0[2] = cvt_pk(s[1][j][0], s[1][j][1]);  w0[3] = cvt_pk(s[1][j][2], s[1][j][3]);
            w1[0] = cvt_pk(s[2][j][0], s[2][j][1]);  w1[1] = cvt_pk(s[2][j][2], s[2][j][3]);
            w1[2] = cvt_pk(s[3][j][0], s[3][j][1]);  w1[3] = cvt_pk(s[3][j][2], s[3][j][3]);
            pa[j][0] = __builtin_bit_cast(bf16x8, w0);
            pa[j][1] = __builtin_bit_cast(bf16x8, w1);
        }

        // ---- PV: bv fragments shared across both sub-blocks ----
        __builtin_amdgcn_s_setprio(1);
        #pragma unroll
        for (int t2 = 0; t2 < 4; ++t2) {
            bf16x8 bv0 = *(const bf16x8*)&vbuf[(t2 * 16 + l16) * KVB +
                                               ((lg * 8) ^ (l7 << 3))];
            bf16x8 bv1 = *(const bf16x8*)&vbuf[(t2 * 16 + l16) * KVB +
                                               ((32 + lg * 8) ^ (l7 << 3))];
            #pragma unroll
            for (int j = 0; j < 2; ++j) {
                acc[t2][j] = __builtin_amdgcn_mfma_f32_16x16x32_bf16(pa[j][0], bv0, acc[t2][j], 0, 0, 0);
                acc[t2][j] = __builtin_amdgcn_mfma_f32_16x16x32_bf16(pa[j][1], bv1, acc[t2][j], 0, 0, 0);
            }
        }
        __builtin_amdgcn_s_setprio(0);

        // ---- re-stage this buffer 2 tiles ahead (no vmcnt drain) ----
        if (t + 2 < NT) {
            SFENCE();
            WAIT_LGKM0();       // my reads of buf[cur] are done
            SBAR(); SFENCE();   // everyone's reads are done
            stage(cur, (t + 2) * KVB);
        }
        cur ^= 1;
    }

    // ---- epilogue ----
    float* op = out + base + (long)qrow0 * DD;
    #pragma unroll
    for (int j = 0; j < 2; ++j) {
        float inv = 1.f / lrun[j];      // valid at lane l16 = q (within sub-block j)
        #pragma unroll
        for (int r = 0; r < 4; ++r) {
            float ir = __shfl(inv, lg * 4 + r);
            #pragma unroll
            for (int t2 = 0; t2 < 4; ++t2)
                op[(long)(j * 16 + lg * 4 + r) * DD + t2 * 16 + l16] = acc[t2][j][r] * ir;
        }
    }
}

extern "C" void kernel_launch(void* const* d_in, const int* in_sizes, int n_in,
                              void* d_out, int out_size, void* d_ws, size_t ws_size,
                              hipStream_t stream) {
    const float* q = (const float*)d_in[0];
    const float* k = (const float*)d_in[1];
    const float* v = (const float*)d_in[2];
    float* out = (float*)d_out;

    short* kws  = (short*)d_ws;
    short* vtws = kws + BHND;
    prep<<<dim3(64, 32, 2), 256, 0, stream>>>(k, v, kws, vtws);
    attn_fwd_v6<<<1024, 128, 0, stream>>>(q, kws, vtws, out);
    (void)ws_size;
}